// Round 7
// baseline (4197.437 us; speedup 1.0000x reference)
//
#include <hip/hip_runtime.h>
#include <math.h>

#define NODES   325
#define TOPK    8
#define B_SZ    8
#define T_LEN   64
#define EPS     1e-5f
#define NTOK    ((size_t)B_SZ * T_LEN * NODES)   /* 166,400 */

/* ---- LDS layout for opt_mamba R7 (dynamic, floats) ----
   s_h   [64][68]   LN output; ALIASED as s_dbl after z      4352
   s_xc  [64][132]  xi -> xc -> y -> u                        8448
   sW0/sW1          ping-pong weight chunks (32 rows)     2 x 2304
   total 17408 floats = 69632 B -> target 2 blocks/CU
   (R5 proved 61.4 KB -> 2 blk; R4 proved 78.8 KB -> 1 blk; this probes 69.6)
   All GEMM phases read weights from LDS (R3-proven fast: 801 us vs
   R6's global-read 1360 us). in_w: 8 chunks of 32 rows, stride 36
   (16B-aligned float4, conflict-free). out_w: 4 col-chunks [32c][68j]. */
#define HPAD    68
#define XCPAD   132
#define DBLPAD  40
#define OFF_XC  4352
#define OFF_W0  12800
#define OFF_W1  15104
#define SMEM_BYTES (17408*4)

__device__ __forceinline__ float waveSum64(float v){
  #pragma unroll
  for(int m=1;m<64;m<<=1) v += __shfl_xor(v, m, 64);
  return v;
}
__device__ __forceinline__ float groupSum16(float v){
  v += __shfl_xor(v, 1, 64);
  v += __shfl_xor(v, 2, 64);
  v += __shfl_xor(v, 4, 64);
  v += __shfl_xor(v, 8, 64);
  return v;
}
__device__ __forceinline__ float dot64(const float* __restrict__ s,
                                       const float* __restrict__ w, float acc){
  #pragma unroll
  for(int q=0;q<64;q++) acc = fmaf(s[q], w[q], acc);
  return acc;
}
__device__ __forceinline__ float4 f4fma(float s, float4 a, float4 acc){
  acc.x = fmaf(s, a.x, acc.x);
  acc.y = fmaf(s, a.y, acc.y);
  acc.z = fmaf(s, a.z, acc.z);
  acc.w = fmaf(s, a.w, acc.w);
  return acc;
}
__device__ __forceinline__ float dp4(float4 a, float4 b, float acc){
  acc = fmaf(a.x, b.x, acc);
  acc = fmaf(a.y, b.y, acc);
  acc = fmaf(a.z, b.z, acc);
  acc = fmaf(a.w, b.w, acc);
  return acc;
}

// stage a 32-row chunk of in_w (rows rbase..rbase+31) transposed: W[c*36+r]
__device__ __forceinline__ void stage_in36(const float* __restrict__ w, int rbase,
                                           float* __restrict__ W, int tid){
  #pragma unroll
  for(int k=0;k<4;k++){
    int idx = tid + k*512;
    int r = idx >> 6, c = idx & 63;
    W[c*36 + r] = w[(rbase + r)*64 + c];   // global: one 256B row per wave
  }
}
// stage a 32-col chunk of out_w (cols cbase..cbase+31): W[c*68+j]
__device__ __forceinline__ void stage_out68(const float* __restrict__ w, int cbase,
                                            float* __restrict__ W, int tid){
  #pragma unroll
  for(int k=0;k<4;k++){
    int idx = tid + k*512;
    int c = idx & 31, j = idx >> 5;
    W[c*68 + j] = w[j*128 + cbase + c];    // global: 128B runs, coalesced
  }
}
// 32-row chunk matvec: rows rr..rr+3 of the chunk, one token row of s_h/s_xc
__device__ __forceinline__ float4 mm32(const float* __restrict__ hrow,
                                       const float* __restrict__ W, int rr){
  float4 a = make_float4(0.f,0.f,0.f,0.f);
  #pragma unroll
  for(int c0=0;c0<64;c0+=4){
    float4 h4 = *(const float4*)&hrow[c0];
    a = f4fma(h4.x, *(const float4*)&W[(c0+0)*36 + rr], a);
    a = f4fma(h4.y, *(const float4*)&W[(c0+1)*36 + rr], a);
    a = f4fma(h4.z, *(const float4*)&W[(c0+2)*36 + rr], a);
    a = f4fma(h4.w, *(const float4*)&W[(c0+3)*36 + rr], a);
  }
  return a;
}

// ---------------- Mamba R7: chunked LDS weights, 69.6 KB, 512 thr ----------------
__global__ __launch_bounds__(512)
void opt_mamba(const float* __restrict__ x,
               const float* __restrict__ ln1_g, const float* __restrict__ ln1_b,
               const float* __restrict__ in_w,
               const float* __restrict__ conv_w, const float* __restrict__ conv_b,
               const float* __restrict__ xp_w,
               const float* __restrict__ dt_w, const float* __restrict__ dt_b,
               const float* __restrict__ A_log, const float* __restrict__ Dss,
               const float* __restrict__ out_w,
               float* __restrict__ xT)
{
  extern __shared__ float sm[];
  float* s_h   = sm;                 // 4352; aliased as s_dbl after z phases
  float* s_dbl = sm;                 // alias (s_h dead once z3 completes)
  float* s_xc  = sm + OFF_XC;        // 8448
  float* sW0   = sm + OFF_W0;        // 2304
  float* sW1   = sm + OFF_W1;        // 2304

  const int bn   = blockIdx.x;
  const int b    = bn / NODES;
  const int n    = bn % NODES;
  const int tid  = threadIdx.x;
  const int lane = tid & 63;
  const int wv   = tid >> 6;

  // chunk tiling: 4 rows (of 32-row chunk) x 1 token per thread
  const int rr = (lane & 7) * 4;            // row-in-chunk 0..28
  const int td = wv*8 + (lane >> 3);        // token 0..63

  // ---- pre: stage in_w rows 0..31 + LayerNorm all tokens
  stage_in36(in_w, 0, sW0, tid);
  {
    const float g_ln = ln1_g[lane], b_ln = ln1_b[lane];
    #pragma unroll
    for(int i=0;i<8;i++){
      int t = wv*8 + i;
      size_t tok = (size_t)(b*T_LEN + t)*NODES + n;
      float v   = x[tok*64 + lane];
      float m   = waveSum64(v) * (1.f/64.f);
      float c   = v - m;
      float var = waveSum64(c*c) * (1.f/64.f);
      s_h[t*HPAD + lane] = c * rsqrtf(var + EPS) * g_ln + b_ln;
    }
  }
  __syncthreads();

  // ---- xi chunks 0..3 (rows 0..127) with ping-pong staging
  stage_in36(in_w, 32, sW1, tid);
  { float4 a = mm32(&s_h[td*HPAD], sW0, rr); *(float4*)&s_xc[td*XCPAD +  0 + rr] = a; }
  __syncthreads();
  stage_in36(in_w, 64, sW0, tid);
  { float4 a = mm32(&s_h[td*HPAD], sW1, rr); *(float4*)&s_xc[td*XCPAD + 32 + rr] = a; }
  __syncthreads();
  stage_in36(in_w, 96, sW1, tid);
  { float4 a = mm32(&s_h[td*HPAD], sW0, rr); *(float4*)&s_xc[td*XCPAD + 64 + rr] = a; }
  __syncthreads();
  stage_in36(in_w, 128, sW0, tid);           // z chunk 0
  { float4 a = mm32(&s_h[td*HPAD], sW1, rr); *(float4*)&s_xc[td*XCPAD + 96 + rr] = a; }
  __syncthreads();

  // ---- conv (window 4) + silu over s_xc, 4 token-quarters; stage z chunk 1
  {
    stage_in36(in_w, 160, sW1, tid);
    const int dd = tid & 127, tg = tid >> 7;
    float p3 = 0.f, p2 = 0.f, p1 = 0.f;
    if(tg){
      int tq = tg*16;
      p3 = s_xc[(tq-3)*XCPAD + dd];
      p2 = s_xc[(tq-2)*XCPAD + dd];
      p1 = s_xc[(tq-1)*XCPAD + dd];
    }
    __syncthreads();
    const float cw0 = conv_w[dd*4+0], cw1 = conv_w[dd*4+1];
    const float cw2 = conv_w[dd*4+2], cw3 = conv_w[dd*4+3];
    const float cb  = conv_b[dd];
    for(int t=tg*16; t<tg*16+16; t++){
      float xi = s_xc[t*XCPAD + dd];
      float v  = cb + cw0*p3 + cw1*p2 + cw2*p1 + cw3*xi;
      p3 = p2; p2 = p1; p1 = xi;
      s_xc[t*XCPAD + dd] = v / (1.f + __expf(-v));
    }
  }
  __syncthreads();

  // ---- z chunks 0..3 (in_w rows 128..255) -> registers zz0..zz3
  float4 zz0, zz1, zz2, zz3;
  zz0 = mm32(&s_h[td*HPAD], sW0, rr);
  __syncthreads();
  stage_in36(in_w, 192, sW0, tid);
  zz1 = mm32(&s_h[td*HPAD], sW1, rr);
  __syncthreads();
  stage_in36(in_w, 224, sW1, tid);
  zz2 = mm32(&s_h[td*HPAD], sW0, rr);
  __syncthreads();
  stage_out68(out_w, 0, sW0, tid);           // out col-chunk 0
  zz3 = mm32(&s_h[td*HPAD], sW1, rr);
  __syncthreads();
  // s_h is now dead -> its space becomes s_dbl

  // ---- xp: dbl = xc @ x_proj.T (36 rows over 8 waves, w broadcast from global)
  {
    stage_out68(out_w, 32, sW1, tid);        // out col-chunk 1
    const int td2 = tid & 63, rg = tid >> 6;
    const int base = rg*5;
    float dacc[5];
    #pragma unroll
    for(int i=0;i<5;i++) dacc[i] = 0.f;
    for(int c0=0;c0<128;c0+=4){
      float4 xc4 = *(const float4*)&s_xc[td2*XCPAD + c0];
      #pragma unroll
      for(int i=0;i<5;i++){
        if(base+i < 36){
          float4 w4 = *(const float4*)&xp_w[(base+i)*128 + c0];
          dacc[i] = dp4(xc4, w4, dacc[i]);
        }
      }
    }
    #pragma unroll
    for(int i=0;i<5;i++)
      if(base+i < 36) s_dbl[td2*DBLPAD + base + i] = dacc[i];
  }
  __syncthreads();

  // ---- scan: all 512 threads, d = tid>>2, s-quartet = tid&3, inline dtv
  {
    const int d  = tid >> 2;
    const int sq = tid & 3;
    float A_d[4], hs[4];
    #pragma unroll
    for(int i=0;i<4;i++){ A_d[i] = -__expf(A_log[d*16 + sq*4 + i]); hs[i] = 0.f; }
    const float dtw0 = dt_w[d*4+0], dtw1 = dt_w[d*4+1];
    const float dtw2 = dt_w[d*4+2], dtw3 = dt_w[d*4+3];
    const float dtb  = dt_b[d], Dd = Dss[d];
    for(int t=0;t<T_LEN;t++){
      const float* db = &s_dbl[t*DBLPAD];
      float4 dt4 = *(const float4*)db;
      float dtv = dtb;
      dtv = fmaf(dt4.x, dtw0, dtv);
      dtv = fmaf(dt4.y, dtw1, dtv);
      dtv = fmaf(dt4.z, dtw2, dtv);
      dtv = fmaf(dt4.w, dtw3, dtv);
      dtv = fmaxf(dtv, 0.f) + log1pf(__expf(-fabsf(dtv)));   // softplus
      float xc = s_xc[t*XCPAD + d];
      float dx = dtv * xc;
      float4 Bv = *(const float4*)&db[4  + sq*4];
      float4 Cv = *(const float4*)&db[20 + sq*4];
      float yp = 0.f;
      hs[0] = fmaf(dx, Bv.x, hs[0]*__expf(dtv*A_d[0])); yp = fmaf(hs[0], Cv.x, yp);
      hs[1] = fmaf(dx, Bv.y, hs[1]*__expf(dtv*A_d[1])); yp = fmaf(hs[1], Cv.y, yp);
      hs[2] = fmaf(dx, Bv.z, hs[2]*__expf(dtv*A_d[2])); yp = fmaf(hs[2], Cv.z, yp);
      hs[3] = fmaf(dx, Bv.w, hs[3]*__expf(dtv*A_d[3])); yp = fmaf(hs[3], Cv.w, yp);
      yp += __shfl_xor(yp, 1, 64);
      yp += __shfl_xor(yp, 2, 64);
      if(sq == 0) s_xc[t*XCPAD + d] = yp + Dd*xc;
    }
  }
  __syncthreads();

  // ---- u = y * silu(z) in place (chunk tiling, 4 chunks)
  {
    float4 y4, u4;
    y4 = *(const float4*)&s_xc[td*XCPAD +  0 + rr];
    u4.x = y4.x*(zz0.x/(1.f+__expf(-zz0.x))); u4.y = y4.y*(zz0.y/(1.f+__expf(-zz0.y)));
    u4.z = y4.z*(zz0.z/(1.f+__expf(-zz0.z))); u4.w = y4.w*(zz0.w/(1.f+__expf(-zz0.w)));
    *(float4*)&s_xc[td*XCPAD +  0 + rr] = u4;
    y4 = *(const float4*)&s_xc[td*XCPAD + 32 + rr];
    u4.x = y4.x*(zz1.x/(1.f+__expf(-zz1.x))); u4.y = y4.y*(zz1.y/(1.f+__expf(-zz1.y)));
    u4.z = y4.z*(zz1.z/(1.f+__expf(-zz1.z))); u4.w = y4.w*(zz1.w/(1.f+__expf(-zz1.w)));
    *(float4*)&s_xc[td*XCPAD + 32 + rr] = u4;
    y4 = *(const float4*)&s_xc[td*XCPAD + 64 + rr];
    u4.x = y4.x*(zz2.x/(1.f+__expf(-zz2.x))); u4.y = y4.y*(zz2.y/(1.f+__expf(-zz2.y)));
    u4.z = y4.z*(zz2.z/(1.f+__expf(-zz2.z))); u4.w = y4.w*(zz2.w/(1.f+__expf(-zz2.w)));
    *(float4*)&s_xc[td*XCPAD + 64 + rr] = u4;
    y4 = *(const float4*)&s_xc[td*XCPAD + 96 + rr];
    u4.x = y4.x*(zz3.x/(1.f+__expf(-zz3.x))); u4.y = y4.y*(zz3.y/(1.f+__expf(-zz3.y)));
    u4.z = y4.z*(zz3.z/(1.f+__expf(-zz3.z))); u4.w = y4.w*(zz3.w/(1.f+__expf(-zz3.w)));
    *(float4*)&s_xc[td*XCPAD + 96 + rr] = u4;
  }
  __syncthreads();

  // ---- out = u @ out_w.T in 4 col-chunks (persistent acc) + residual -> xT
  {
    const int rO = (tid & 15) * 4;           // output dims rO..rO+3
    const int tO = (tid >> 4) * 2;           // tokens tO, tO+1
    float4 acc0 = make_float4(0.f,0.f,0.f,0.f), acc1 = acc0;

    #define OUTACC(W, CB)                                                     \
    {                                                                         \
      _Pragma("unroll")                                                       \
      for(int c0=0;c0<32;c0+=4){                                              \
        float4 u0 = *(const float4*)&s_xc[(tO+0)*XCPAD + (CB) + c0];          \
        float4 u1 = *(const float4*)&s_xc[(tO+1)*XCPAD + (CB) + c0];          \
        float4 w0 = *(const float4*)&(W)[(c0+0)*68 + rO];                     \
        float4 w1 = *(const float4*)&(W)[(c0+1)*68 + rO];                     \
        float4 w2 = *(const float4*)&(W)[(c0+2)*68 + rO];                     \
        float4 w3 = *(const float4*)&(W)[(c0+3)*68 + rO];                     \
        acc0 = f4fma(u0.x,w0,acc0); acc0 = f4fma(u0.y,w1,acc0);               \
        acc0 = f4fma(u0.z,w2,acc0); acc0 = f4fma(u0.w,w3,acc0);               \
        acc1 = f4fma(u1.x,w0,acc1); acc1 = f4fma(u1.y,w1,acc1);               \
        acc1 = f4fma(u1.z,w2,acc1); acc1 = f4fma(u1.w,w3,acc1);               \
      }                                                                       \
    }

    OUTACC(sW0, 0);
    __syncthreads();
    stage_out68(out_w, 64, sW0, tid);
    OUTACC(sW1, 32);
    __syncthreads();
    stage_out68(out_w, 96, sW1, tid);
    OUTACC(sW0, 64);
    __syncthreads();
    OUTACC(sW1, 96);
    #undef OUTACC

    size_t tok0 = (size_t)(b*T_LEN + tO+0)*NODES + n;
    size_t tok1 = (size_t)(b*T_LEN + tO+1)*NODES + n;
    float4 xv0 = *(const float4*)&x[tok0*64 + rO];
    float4 xv1 = *(const float4*)&x[tok1*64 + rO];
    float4 o0, o1;
    o0.x = xv0.x + acc0.x; o0.y = xv0.y + acc0.y; o0.z = xv0.z + acc0.z; o0.w = xv0.w + acc0.w;
    o1.x = xv1.x + acc1.x; o1.y = xv1.y + acc1.y; o1.z = xv1.z + acc1.z; o1.w = xv1.w + acc1.w;
    *(float4*)&xT[tok0*64 + rO] = o0;
    *(float4*)&xT[tok1*64 + rO] = o1;
  }
}

// ---------------- K/V + gate projection (R8-validated, unchanged) ----------------
__global__ __launch_bounds__(256)
void opt_proj(const float* __restrict__ xT,
              const float* __restrict__ k_w, const float* __restrict__ k_b,
              const float* __restrict__ v_w, const float* __restrict__ v_b,
              const float* __restrict__ g1_w, const float* __restrict__ g1_b,
              const float* __restrict__ g2_w, const float* __restrict__ g2_b,
              float* __restrict__ Kb, float* __restrict__ Vb,
              float* __restrict__ gate)
{
  __shared__ float s_x[64*68];
  const int tid = threadIdx.x;
  const size_t tb = (size_t)blockIdx.x * 64;

  for(int i = tid; i < 64*64; i += 256){
    int t = i >> 6, c = i & 63;
    s_x[t*68 + c] = xT[(tb + t)*64 + c];
  }
  __syncthreads();

  const int r0 = (tid & 15) * 4;
  const int t0 = (tid >> 4) * 4;

  {
    float4 b4 = *(const float4*)&k_b[r0];
    float4 acc[4];
    #pragma unroll
    for(int tt=0;tt<4;tt++) acc[tt] = b4;
    for(int c0=0;c0<64;c0+=4){
      float4 w0 = *(const float4*)&k_w[(r0+0)*64 + c0];
      float4 w1 = *(const float4*)&k_w[(r0+1)*64 + c0];
      float4 w2 = *(const float4*)&k_w[(r0+2)*64 + c0];
      float4 w3 = *(const float4*)&k_w[(r0+3)*64 + c0];
      #pragma unroll
      for(int tt=0;tt<4;tt++){
        float4 x4 = *(const float4*)&s_x[(t0+tt)*68 + c0];
        acc[tt].x = dp4(x4, w0, acc[tt].x);
        acc[tt].y = dp4(x4, w1, acc[tt].y);
        acc[tt].z = dp4(x4, w2, acc[tt].z);
        acc[tt].w = dp4(x4, w3, acc[tt].w);
      }
    }
    #pragma unroll
    for(int tt=0;tt<4;tt++)
      *(float4*)&Kb[(tb + t0 + tt)*64 + r0] = acc[tt];
  }

  {
    float4 b4 = *(const float4*)&v_b[r0];
    float4 acc[4];
    #pragma unroll
    for(int tt=0;tt<4;tt++) acc[tt] = b4;
    for(int c0=0;c0<64;c0+=4){
      float4 w0 = *(const float4*)&v_w[(r0+0)*64 + c0];
      float4 w1 = *(const float4*)&v_w[(r0+1)*64 + c0];
      float4 w2 = *(const float4*)&v_w[(r0+2)*64 + c0];
      float4 w3 = *(const float4*)&v_w[(r0+3)*64 + c0];
      #pragma unroll
      for(int tt=0;tt<4;tt++){
        float4 x4 = *(const float4*)&s_x[(t0+tt)*68 + c0];
        acc[tt].x = dp4(x4, w0, acc[tt].x);
        acc[tt].y = dp4(x4, w1, acc[tt].y);
        acc[tt].z = dp4(x4, w2, acc[tt].z);
        acc[tt].w = dp4(x4, w3, acc[tt].w);
      }
    }
    #pragma unroll
    for(int tt=0;tt<4;tt++)
      *(float4*)&Vb[(tb + t0 + tt)*64 + r0] = acc[tt];
  }

  {
    const int td = tid >> 2;
    const int sr = (tid & 3) * 4;
    float partial = 0.f;
    #pragma unroll
    for(int i=0;i<4;i++){
      int r = sr + i;
      float u = dot64(&s_x[td*68], g1_w + r*64, g1_b[r]);
      u = 0.5f * u * (1.f + erff(u * 0.70710678118654752f));
      partial = fmaf(u, g2_w[r], partial);
    }
    partial += __shfl_xor(partial, 1, 64);
    partial += __shfl_xor(partial, 2, 64);
    if((tid & 3) == 0)
      gate[tb + td] = 1.f / (1.f + __expf(-(partial + g2_b[0])));
  }
}

// ---------------- R9 tile attention (validated, unchanged) ----------------
__global__ __launch_bounds__(256)
void opt_attn3(const float* __restrict__ xT,
               const float* __restrict__ Kb, const float* __restrict__ Vb,
               const float* __restrict__ gate, const int* __restrict__ nbr,
               const float* __restrict__ q_w, const float* __restrict__ q_b,
               const float* __restrict__ o_w, const float* __restrict__ o_b,
               const float* __restrict__ ln2_g, const float* __restrict__ ln2_b,
               float* __restrict__ out)
{
  __shared__ float s_x[64*68];
  __shared__ float s_q[64*68];
  const int tid = threadIdx.x;
  const size_t tb = (size_t)blockIdx.x * 64;

  for(int i = tid; i < 64*64; i += 256){
    int t = i >> 6, c = i & 63;
    s_x[t*68 + c] = xT[(tb + t)*64 + c];
  }
  __syncthreads();

  {
    const int r0 = (tid & 15) * 4, t0 = (tid >> 4) * 4;
    float4 b4 = *(const float4*)&q_b[r0];
    float4 acc[4];
    #pragma unroll
    for(int tt=0;tt<4;tt++) acc[tt] = b4;
    for(int c0=0;c0<64;c0+=4){
      float4 w0 = *(const float4*)&q_w[(r0+0)*64 + c0];
      float4 w1 = *(const float4*)&q_w[(r0+1)*64 + c0];
      float4 w2 = *(const float4*)&q_w[(r0+2)*64 + c0];
      float4 w3 = *(const float4*)&q_w[(r0+3)*64 + c0];
      #pragma unroll
      for(int tt=0;tt<4;tt++){
        float4 x4 = *(const float4*)&s_x[(t0+tt)*68 + c0];
        acc[tt].x = dp4(x4, w0, acc[tt].x);
        acc[tt].y = dp4(x4, w1, acc[tt].y);
        acc[tt].z = dp4(x4, w2, acc[tt].z);
        acc[tt].w = dp4(x4, w3, acc[tt].w);
      }
    }
    #pragma unroll
    for(int tt=0;tt<4;tt++)
      *(float4*)&s_q[(t0+tt)*68 + r0] = acc[tt];
  }
  __syncthreads();

  const int td = tid >> 2, h = tid & 3;
  const size_t idxg = tb + td;
  const int n  = (int)(idxg % NODES);
  const int bt = (int)(idxg / NODES);

  const float* qp = &s_q[td*68 + h*16];
  float4 q0 = *(const float4*)(qp+0);
  float4 q1 = *(const float4*)(qp+4);
  float4 q2 = *(const float4*)(qp+8);
  float4 q3 = *(const float4*)(qp+12);
  int rows[TOPK];
  #pragma unroll
  for(int k=0;k<TOPK;k++) rows[k] = bt*NODES + nbr[n*TOPK + k];
  __syncthreads();

  float sc[TOPK];
  #pragma unroll
  for(int k=0;k<TOPK;k++){
    const float* kr = &Kb[(size_t)rows[k]*64 + h*16];
    float4 k0 = *(const float4*)(kr+0);
    float4 k1 = *(const float4*)(kr+4);
    float4 k2 = *(const float4*)(kr+8);
    float4 k3 = *(const float4*)(kr+12);
    float s = dp4(q0,k0, dp4(q1,k1, dp4(q2,k2, dp4(q3,k3, 0.f))));
    sc[k] = s * 0.25f;
  }
  float mx = sc[0];
  #pragma unroll
  for(int k=1;k<TOPK;k++) mx = fmaxf(mx, sc[k]);
  float ssum = 0.f;
  #pragma unroll
  for(int k=0;k<TOPK;k++){ sc[k] = __expf(sc[k]-mx); ssum += sc[k]; }
  float inv = 1.f/ssum;
  float4 o0 = make_float4(0.f,0.f,0.f,0.f), o1 = o0, o2 = o0, o3 = o0;
  #pragma unroll
  for(int k=0;k<TOPK;k++){
    const float* vr = &Vb[(size_t)rows[k]*64 + h*16];
    float p = sc[k]*inv;
    o0 = f4fma(p, *(const float4*)(vr+0),  o0);
    o1 = f4fma(p, *(const float4*)(vr+4),  o1);
    o2 = f4fma(p, *(const float4*)(vr+8),  o2);
    o3 = f4fma(p, *(const float4*)(vr+12), o3);
  }
  {
    float* op = &s_q[td*68 + h*16];
    *(float4*)(op+0)  = o0;
    *(float4*)(op+4)  = o1;
    *(float4*)(op+8)  = o2;
    *(float4*)(op+12) = o3;
  }
  __syncthreads();

  float4 ores[4];
  const int r0 = (tid & 15) * 4, t0 = (tid >> 4) * 4;
  {
    float4 b4 = *(const float4*)&o_b[r0];
    float4 acc[4];
    #pragma unroll
    for(int tt=0;tt<4;tt++) acc[tt] = b4;
    for(int c0=0;c0<64;c0+=4){
      float4 w0 = *(const float4*)&o_w[(r0+0)*64 + c0];
      float4 w1 = *(const float4*)&o_w[(r0+1)*64 + c0];
      float4 w2 = *(const float4*)&o_w[(r0+2)*64 + c0];
      float4 w3 = *(const float4*)&o_w[(r0+3)*64 + c0];
      #pragma unroll
      for(int tt=0;tt<4;tt++){
        float4 g4 = *(const float4*)&s_q[(t0+tt)*68 + c0];
        acc[tt].x = dp4(g4, w0, acc[tt].x);
        acc[tt].y = dp4(g4, w1, acc[tt].y);
        acc[tt].z = dp4(g4, w2, acc[tt].z);
        acc[tt].w = dp4(g4, w3, acc[tt].w);
      }
    }
    #pragma unroll
    for(int tt=0;tt<4;tt++){
      float g = gate[tb + t0 + tt];
      float4 xv = *(const float4*)&s_x[(t0+tt)*68 + r0];
      ores[tt].x = xv.x + g*(acc[tt].x - xv.x);
      ores[tt].y = xv.y + g*(acc[tt].y - xv.y);
      ores[tt].z = xv.z + g*(acc[tt].z - xv.z);
      ores[tt].w = xv.w + g*(acc[tt].w - xv.w);
    }
  }
  __syncthreads();
  #pragma unroll
  for(int tt=0;tt<4;tt++)
    *(float4*)&s_q[(t0+tt)*68 + r0] = ores[tt];
  __syncthreads();

  {
    const float* orow = &s_q[td*68 + h*16];
    float4 a0 = *(const float4*)(orow+0);
    float4 a1 = *(const float4*)(orow+4);
    float4 a2 = *(const float4*)(orow+8);
    float4 a3 = *(const float4*)(orow+12);
    float sum = (a0.x+a0.y+a0.z+a0.w) + (a1.x+a1.y+a1.z+a1.w)
              + (a2.x+a2.y+a2.z+a2.w) + (a3.x+a3.y+a3.z+a3.w);
    sum += __shfl_xor(sum, 1, 64);
    sum += __shfl_xor(sum, 2, 64);
    float mean = sum * (1.f/64.f);
    a0.x-=mean; a0.y-=mean; a0.z-=mean; a0.w-=mean;
    a1.x-=mean; a1.y-=mean; a1.z-=mean; a1.w-=mean;
    a2.x-=mean; a2.y-=mean; a2.z-=mean; a2.w-=mean;
    a3.x-=mean; a3.y-=mean; a3.z-=mean; a3.w-=mean;
    float sq = (a0.x*a0.x+a0.y*a0.y+a0.z*a0.z+a0.w*a0.w)
             + (a1.x*a1.x+a1.y*a1.y+a1.z*a1.z+a1.w*a1.w)
             + (a2.x*a2.x+a2.y*a2.y+a2.z*a2.z+a2.w*a2.w)
             + (a3.x*a3.x+a3.y*a3.y+a3.z*a3.z+a3.w*a3.w);
    sq += __shfl_xor(sq, 1, 64);
    sq += __shfl_xor(sq, 2, 64);
    float rstd = rsqrtf(sq*(1.f/64.f) + EPS);
    float4 g0 = *(const float4*)&ln2_g[h*16+0];
    float4 g1 = *(const float4*)&ln2_g[h*16+4];
    float4 g2 = *(const float4*)&ln2_g[h*16+8];
    float4 g3 = *(const float4*)&ln2_g[h*16+12];
    float4 bb0 = *(const float4*)&ln2_b[h*16+0];
    float4 bb1 = *(const float4*)&ln2_b[h*16+4];
    float4 bb2 = *(const float4*)&ln2_b[h*16+8];
    float4 bb3 = *(const float4*)&ln2_b[h*16+12];
    float* po = &out[idxg*64 + h*16];
    float4 r;
    r.x=a0.x*rstd*g0.x+bb0.x; r.y=a0.y*rstd*g0.y+bb0.y; r.z=a0.z*rstd*g0.z+bb0.z; r.w=a0.w*rstd*g0.w+bb0.w;
    *(float4*)(po+0) = r;
    r.x=a1.x*rstd*g1.x+bb1.x; r.y=a1.y*rstd*g1.y+bb1.y; r.z=a1.z*rstd*g1.z+bb1.z; r.w=a1.w*rstd*g1.w+bb1.w;
    *(float4*)(po+4) = r;
    r.x=a2.x*rstd*g2.x+bb2.x; r.y=a2.y*rstd*g2.y+bb2.y; r.z=a2.z*rstd*g2.z+bb2.z; r.w=a2.w*rstd*g2.w+bb2.w;
    *(float4*)(po+8) = r;
    r.x=a3.x*rstd*g3.x+bb3.x; r.y=a3.y*rstd*g3.y+bb3.y; r.z=a3.z*rstd*g3.z+bb3.z; r.w=a3.w*rstd*g3.w+bb3.w;
    *(float4*)(po+12) = r;
  }
}

// ---------------- Fallback fused attn (used only if ws too small) ----------------
__global__ __launch_bounds__(64)
void opt_attn(const float* __restrict__ xT, const int* __restrict__ nbr,
              const float* __restrict__ q_w, const float* __restrict__ q_b,
              const float* __restrict__ k_w, const float* __restrict__ k_b,
              const float* __restrict__ v_w, const float* __restrict__ v_b,
              const float* __restrict__ o_w, const float* __restrict__ o_b,
              const float* __restrict__ g1_w, const float* __restrict__ g1_b,
              const float* __restrict__ g2_w, const float* __restrict__ g2_b,
              const float* __restrict__ ln2_g, const float* __restrict__ ln2_b,
              float* __restrict__ out)
{
  const int idx = blockIdx.x;
  const int n   = idx % NODES;
  const int bt  = idx / NODES;
  const int j   = threadIdx.x;

  __shared__ float s_x[64];
  __shared__ float s_nb[TOPK][64];
  __shared__ float s_og[64];
  __shared__ float s_gate;

  float xv = xT[(size_t)idx*64 + j];
  s_x[j] = xv;
  const int base = bt * NODES;
  #pragma unroll
  for(int k=0;k<TOPK;k++){
    int nb2 = nbr[n*TOPK + k];
    s_nb[k][j] = xT[(size_t)(base + nb2)*64 + j];
  }
  __syncthreads();

  float Qj = dot64(s_x, q_w + j*64, q_b[j]);

  float sc[TOPK], vv[TOPK];
  #pragma unroll
  for(int k=0;k<TOPK;k++){
    float Kk = dot64(s_nb[k], k_w + j*64, k_b[j]);
    vv[k]    = dot64(s_nb[k], v_w + j*64, v_b[j]);
    sc[k]    = groupSum16(Qj * Kk) * 0.25f;
  }
  float m = sc[0];
  #pragma unroll
  for(int k=1;k<TOPK;k++) m = fmaxf(m, sc[k]);
  float ssum = 0.f;
  #pragma unroll
  for(int k=0;k<TOPK;k++){ sc[k] = __expf(sc[k]-m); ssum += sc[k]; }
  float inv = 1.f/ssum;
  float og = 0.f;
  #pragma unroll
  for(int k=0;k<TOPK;k++) og = fmaf(sc[k]*inv, vv[k], og);
  s_og[j] = og;
  __syncthreads();

  float xg = dot64(s_og, o_w + j*64, o_b[j]);

  if(j < 16){
    float u = dot64(s_x, g1_w + j*64, g1_b[j]);
    u = 0.5f * u * (1.f + erff(u * 0.70710678118654752f));
    float contrib = groupSum16(u * g2_w[j]);
    if(j == 0) s_gate = 1.f / (1.f + __expf(-(contrib + g2_b[0])));
  }
  __syncthreads();

  float gg = s_gate;
  float o  = xv + gg * (xg - xv);

  float mm  = waveSum64(o) * (1.f/64.f);
  float c   = o - mm;
  float var = waveSum64(c*c) * (1.f/64.f);
  out[(size_t)idx*64 + j] = c * rsqrtf(var + EPS) * ln2_g[j] + ln2_b[j];
}

extern "C" void kernel_launch(void* const* d_in, const int* in_sizes, int n_in,
                              void* d_out, int out_size, void* d_ws, size_t ws_size,
                              hipStream_t stream)
{
  const float* x      = (const float*)d_in[0];
  const int*   nbr    = (const int*  )d_in[1];
  const float* ln1_g  = (const float*)d_in[2];
  const float* ln1_b  = (const float*)d_in[3];
  const float* in_w   = (const float*)d_in[4];
  const float* conv_w = (const float*)d_in[5];
  const float* conv_b = (const float*)d_in[6];
  const float* xp_w   = (const float*)d_in[7];
  const float* dt_w   = (const float*)d_in[8];
  const float* dt_b   = (const float*)d_in[9];
  const float* A_log  = (const float*)d_in[10];
  const float* Dss    = (const float*)d_in[11];
  const float* out_w  = (const float*)d_in[12];
  const float* q_w    = (const float*)d_in[13];
  const float* q_b    = (const float*)d_in[14];
  const float* k_w    = (const float*)d_in[15];
  const float* k_b    = (const float*)d_in[16];
  const float* v_w    = (const float*)d_in[17];
  const float* v_b    = (const float*)d_in[18];
  const float* o_w    = (const float*)d_in[19];
  const float* o_b    = (const float*)d_in[20];
  const float* g1_w   = (const float*)d_in[21];
  const float* g1_b   = (const float*)d_in[22];
  const float* g2_w   = (const float*)d_in[23];
  const float* g2_b   = (const float*)d_in[24];
  const float* ln2_g  = (const float*)d_in[25];
  const float* ln2_b  = (const float*)d_in[26];

  float* xT   = (float*)d_ws;                 // 42.6 MB
  float* Kb   = xT + NTOK*64;                 // +42.6 MB
  float* Vb   = Kb + NTOK*64;                 // +42.6 MB
  float* gg   = Vb + NTOK*64;                 // +0.67 MB
  float* outp = (float*)d_out;

  const size_t need = (NTOK*64*3 + NTOK) * sizeof(float);   // ~128.5 MB (proven R2-R6)

  (void)hipFuncSetAttribute(reinterpret_cast<const void*>(opt_mamba),
                            hipFuncAttributeMaxDynamicSharedMemorySize, SMEM_BYTES);

  opt_mamba<<<dim3(B_SZ*NODES), dim3(512), SMEM_BYTES, stream>>>(
      x, ln1_g, ln1_b, in_w, conv_w, conv_b, xp_w, dt_w, dt_b, A_log, Dss, out_w, xT);

  if(ws_size >= need){
    opt_proj<<<dim3((unsigned)(NTOK/64)), dim3(256), 0, stream>>>(
        xT, k_w, k_b, v_w, v_b, g1_w, g1_b, g2_w, g2_b, Kb, Vb, gg);
    opt_attn3<<<dim3((unsigned)(NTOK/64)), dim3(256), 0, stream>>>(
        xT, Kb, Vb, gg, nbr, q_w, q_b, o_w, o_b, ln2_g, ln2_b, outp);
  } else {
    opt_attn<<<dim3((unsigned)NTOK), dim3(64), 0, stream>>>(
        xT, nbr, q_w, q_b, k_w, k_b, v_w, v_b, o_w, o_b,
        g1_w, g1_b, g2_w, g2_b, ln2_g, ln2_b, outp);
  }
}

// Round 8
// 1635.076 us; speedup vs baseline: 2.5671x; 2.5671x over previous
//
#include <hip/hip_runtime.h>
#include <math.h>

#define NODES   325
#define TOPK    8
#define B_SZ    8
#define T_LEN   64
#define EPS     1e-5f
#define NTOK    ((size_t)B_SZ * T_LEN * NODES)   /* 166,400 */

/* ---- LDS layout for opt_mamba (R3-proven structure, s_dtv removed) ----
   s_h   [64][64]   LN output            4096
   s_xc  [64][132]  xi -> xc -> y -> u   8448
   s_dbl [64][40]   x_proj output        2560
   sW    [8704]     in_wT halves / out_wT
   total 23808 floats = 95232 B -> 1 block/CU, 8 waves (512 thr)
   (R3 measured 801 us at 128 KB with identical access patterns; this
   removes the s_dtv phase only.) */
#define WPAD    132
#define OWPAD   68
#define XCPAD   132
#define DBLPAD  40
#define OFF_H   0
#define OFF_XC  4096
#define OFF_DBL 12544
#define OFF_W   15104
#define SMEM_BYTES (23808*4)

__device__ __forceinline__ float waveSum64(float v){
  #pragma unroll
  for(int m=1;m<64;m<<=1) v += __shfl_xor(v, m, 64);
  return v;
}
__device__ __forceinline__ float groupSum16(float v){
  v += __shfl_xor(v, 1, 64);
  v += __shfl_xor(v, 2, 64);
  v += __shfl_xor(v, 4, 64);
  v += __shfl_xor(v, 8, 64);
  return v;
}
__device__ __forceinline__ float dot64(const float* __restrict__ s,
                                       const float* __restrict__ w, float acc){
  #pragma unroll
  for(int q=0;q<64;q++) acc = fmaf(s[q], w[q], acc);
  return acc;
}
__device__ __forceinline__ float4 f4fma(float s, float4 a, float4 acc){
  acc.x = fmaf(s, a.x, acc.x);
  acc.y = fmaf(s, a.y, acc.y);
  acc.z = fmaf(s, a.z, acc.z);
  acc.w = fmaf(s, a.w, acc.w);
  return acc;
}
__device__ __forceinline__ float dp4(float4 a, float4 b, float acc){
  acc = fmaf(a.x, b.x, acc);
  acc = fmaf(a.y, b.y, acc);
  acc = fmaf(a.z, b.z, acc);
  acc = fmaf(a.w, b.w, acc);
  return acc;
}

// ---------------- Mamba R8: R3 structure + 512-thread scan, no s_dtv ----------------
__global__ __launch_bounds__(512)
void opt_mamba(const float* __restrict__ x,
               const float* __restrict__ ln1_g, const float* __restrict__ ln1_b,
               const float* __restrict__ in_w,
               const float* __restrict__ conv_w, const float* __restrict__ conv_b,
               const float* __restrict__ xp_w,
               const float* __restrict__ dt_w, const float* __restrict__ dt_b,
               const float* __restrict__ A_log, const float* __restrict__ Dss,
               const float* __restrict__ out_w,
               float* __restrict__ xT)
{
  extern __shared__ float sm[];
  float* s_h   = sm + OFF_H;
  float* s_xc  = sm + OFF_XC;
  float* s_dbl = sm + OFF_DBL;
  float* sW    = sm + OFF_W;

  const int bn   = blockIdx.x;
  const int b    = bn / NODES;
  const int n    = bn % NODES;
  const int tid  = threadIdx.x;
  const int lane = tid & 63;
  const int wv   = tid >> 6;

  const int r0 = (tid & 31) * 4;     // channel rows r0..r0+3 (phases 2/4a/6)
  const int t0 = (tid >> 5) * 4;     // tokens t0..t0+3

  // ---- Phase 1: stage in_wT lo (xi rows) + LayerNorm all 64 tokens
  for(int idx = tid; idx < 128*64; idx += 512){
    int r = idx >> 6, c = idx & 63;
    sW[c*WPAD + r] = in_w[idx];
  }
  {
    const float g_ln = ln1_g[lane], b_ln = ln1_b[lane];
    #pragma unroll
    for(int i=0;i<8;i++){
      int t = wv*8 + i;
      size_t tok = (size_t)(b*T_LEN + t)*NODES + n;
      float v   = x[tok*64 + lane];
      float m   = waveSum64(v) * (1.f/64.f);
      float c   = v - m;
      float var = waveSum64(c*c) * (1.f/64.f);
      s_h[t*64 + lane] = c * rsqrtf(var + EPS) * g_ln + b_ln;
    }
  }
  __syncthreads();

  // ---- Phase 2: xi = h @ in_w[0:128].T  (4 rows x 4 tokens per thread)
  {
    float4 acc[4];
    #pragma unroll
    for(int tt=0;tt<4;tt++) acc[tt] = make_float4(0.f,0.f,0.f,0.f);
    for(int c0=0;c0<64;c0+=4){
      float4 w0 = *(const float4*)&sW[(c0+0)*WPAD + r0];
      float4 w1 = *(const float4*)&sW[(c0+1)*WPAD + r0];
      float4 w2 = *(const float4*)&sW[(c0+2)*WPAD + r0];
      float4 w3 = *(const float4*)&sW[(c0+3)*WPAD + r0];
      #pragma unroll
      for(int tt=0;tt<4;tt++){
        float4 h4 = *(const float4*)&s_h[(t0+tt)*64 + c0];
        acc[tt] = f4fma(h4.x, w0, acc[tt]);
        acc[tt] = f4fma(h4.y, w1, acc[tt]);
        acc[tt] = f4fma(h4.z, w2, acc[tt]);
        acc[tt] = f4fma(h4.w, w3, acc[tt]);
      }
    }
    #pragma unroll
    for(int tt=0;tt<4;tt++)
      *(float4*)&s_xc[(t0+tt)*XCPAD + r0] = acc[tt];
  }
  __syncthreads();

  // ---- Phase 3: causal conv (window 4) + silu, 4 token-quarters; restage W hi
  {
    const int dd = tid & 127, tg = tid >> 7;   // quarter tg: tokens 16tg..16tg+15
    float p3 = 0.f, p2 = 0.f, p1 = 0.f;
    if(tg){
      int tq = tg*16;
      p3 = s_xc[(tq-3)*XCPAD + dd];
      p2 = s_xc[(tq-2)*XCPAD + dd];
      p1 = s_xc[(tq-1)*XCPAD + dd];
    }
    __syncthreads();
    const float cw0 = conv_w[dd*4+0], cw1 = conv_w[dd*4+1];
    const float cw2 = conv_w[dd*4+2], cw3 = conv_w[dd*4+3];
    const float cb  = conv_b[dd];
    for(int t=tg*16; t<tg*16+16; t++){
      float xi = s_xc[t*XCPAD + dd];
      float v  = cb + cw0*p3 + cw1*p2 + cw2*p1 + cw3*xi;
      p3 = p2; p2 = p1; p1 = xi;
      s_xc[t*XCPAD + dd] = v / (1.f + __expf(-v));
    }
    for(int idx = tid; idx < 128*64; idx += 512){
      int r = idx >> 6, c = idx & 63;
      sW[c*WPAD + r] = in_w[128*64 + idx];
    }
  }
  __syncthreads();

  // ---- Phase 4a: z = h @ in_w[128:256].T -> registers
  float4 zr[4];
  {
    #pragma unroll
    for(int tt=0;tt<4;tt++) zr[tt] = make_float4(0.f,0.f,0.f,0.f);
    for(int c0=0;c0<64;c0+=4){
      float4 w0 = *(const float4*)&sW[(c0+0)*WPAD + r0];
      float4 w1 = *(const float4*)&sW[(c0+1)*WPAD + r0];
      float4 w2 = *(const float4*)&sW[(c0+2)*WPAD + r0];
      float4 w3 = *(const float4*)&sW[(c0+3)*WPAD + r0];
      #pragma unroll
      for(int tt=0;tt<4;tt++){
        float4 h4 = *(const float4*)&s_h[(t0+tt)*64 + c0];
        zr[tt] = f4fma(h4.x, w0, zr[tt]);
        zr[tt] = f4fma(h4.y, w1, zr[tt]);
        zr[tt] = f4fma(h4.z, w2, zr[tt]);
        zr[tt] = f4fma(h4.w, w3, zr[tt]);
      }
    }
  }

  // ---- Phase 4b: dbl = xc @ x_proj.T (36 rows over 8 wave-groups)
  {
    const int td = tid & 63, rg = tid >> 6;
    const int base = rg*5;                     // rows base..base+4, guard <36
    float dacc[5];
    #pragma unroll
    for(int i=0;i<5;i++) dacc[i] = 0.f;
    for(int c0=0;c0<128;c0+=4){
      float4 xc4 = *(const float4*)&s_xc[td*XCPAD + c0];
      #pragma unroll
      for(int i=0;i<5;i++){
        if(base+i < 36){
          float4 w4 = *(const float4*)&xp_w[(base+i)*128 + c0];
          dacc[i] = dp4(xc4, w4, dacc[i]);
        }
      }
    }
    #pragma unroll
    for(int i=0;i<5;i++)
      if(base+i < 36) s_dbl[td*DBLPAD + base + i] = dacc[i];
  }
  __syncthreads();

  // ---- Phase 5: selective scan, ALL 512 threads (d = tid>>2, s-quartet = tid&3)
  //      inline dtv (softplus); proven correct R4-R7, proven clean R6.
  {
    const int d  = tid >> 2;
    const int sq = tid & 3;
    float A_d[4], hs[4];
    #pragma unroll
    for(int i=0;i<4;i++){ A_d[i] = -__expf(A_log[d*16 + sq*4 + i]); hs[i] = 0.f; }
    const float dtw0 = dt_w[d*4+0], dtw1 = dt_w[d*4+1];
    const float dtw2 = dt_w[d*4+2], dtw3 = dt_w[d*4+3];
    const float dtb  = dt_b[d], Dd = Dss[d];
    for(int t=0;t<T_LEN;t++){
      const float* db = &s_dbl[t*DBLPAD];
      float4 dt4 = *(const float4*)db;
      float dtv = dtb;
      dtv = fmaf(dt4.x, dtw0, dtv);
      dtv = fmaf(dt4.y, dtw1, dtv);
      dtv = fmaf(dt4.z, dtw2, dtv);
      dtv = fmaf(dt4.w, dtw3, dtv);
      dtv = fmaxf(dtv, 0.f) + log1pf(__expf(-fabsf(dtv)));   // softplus
      float xc = s_xc[t*XCPAD + d];
      float dx = dtv * xc;
      float4 Bv = *(const float4*)&db[4  + sq*4];
      float4 Cv = *(const float4*)&db[20 + sq*4];
      float yp = 0.f;
      hs[0] = fmaf(dx, Bv.x, hs[0]*__expf(dtv*A_d[0])); yp = fmaf(hs[0], Cv.x, yp);
      hs[1] = fmaf(dx, Bv.y, hs[1]*__expf(dtv*A_d[1])); yp = fmaf(hs[1], Cv.y, yp);
      hs[2] = fmaf(dx, Bv.z, hs[2]*__expf(dtv*A_d[2])); yp = fmaf(hs[2], Cv.z, yp);
      hs[3] = fmaf(dx, Bv.w, hs[3]*__expf(dtv*A_d[3])); yp = fmaf(hs[3], Cv.w, yp);
      yp += __shfl_xor(yp, 1, 64);
      yp += __shfl_xor(yp, 2, 64);
      if(sq == 0) s_xc[t*XCPAD + d] = yp + Dd*xc;
    }
  }
  __syncthreads();

  // ---- Phase 6: u = y * silu(z); stage out_wT
  {
    #pragma unroll
    for(int tt=0;tt<4;tt++){
      float4 y4 = *(const float4*)&s_xc[(t0+tt)*XCPAD + r0];
      float4 z4 = zr[tt];
      float4 u;
      u.x = y4.x * (z4.x / (1.f + __expf(-z4.x)));
      u.y = y4.y * (z4.y / (1.f + __expf(-z4.y)));
      u.z = y4.z * (z4.z / (1.f + __expf(-z4.z)));
      u.w = y4.w * (z4.w / (1.f + __expf(-z4.w)));
      *(float4*)&s_xc[(t0+tt)*XCPAD + r0] = u;
    }
    for(int idx = tid; idx < 64*128; idx += 512){
      int j = idx >> 7, c = idx & 127;
      sW[c*OWPAD + j] = out_w[idx];
    }
  }
  __syncthreads();

  // ---- Phase 7: out = u @ out_w.T + x residual -> xT (4 dims x 2 tokens)
  {
    const int j0  = (tid & 15) * 4;
    const int t0o = (tid >> 4) * 2;
    float4 oacc[2];
    #pragma unroll
    for(int tt=0;tt<2;tt++) oacc[tt] = make_float4(0.f,0.f,0.f,0.f);
    for(int c0=0;c0<128;c0+=4){
      float4 w0 = *(const float4*)&sW[(c0+0)*OWPAD + j0];
      float4 w1 = *(const float4*)&sW[(c0+1)*OWPAD + j0];
      float4 w2 = *(const float4*)&sW[(c0+2)*OWPAD + j0];
      float4 w3 = *(const float4*)&sW[(c0+3)*OWPAD + j0];
      #pragma unroll
      for(int tt=0;tt<2;tt++){
        float4 u4 = *(const float4*)&s_xc[(t0o+tt)*XCPAD + c0];
        oacc[tt] = f4fma(u4.x, w0, oacc[tt]);
        oacc[tt] = f4fma(u4.y, w1, oacc[tt]);
        oacc[tt] = f4fma(u4.z, w2, oacc[tt]);
        oacc[tt] = f4fma(u4.w, w3, oacc[tt]);
      }
    }
    #pragma unroll
    for(int tt=0;tt<2;tt++){
      int t = t0o + tt;
      size_t tok = (size_t)(b*T_LEN + t)*NODES + n;
      float4 xv = *(const float4*)&x[tok*64 + j0];
      float4 o;
      o.x = xv.x + oacc[tt].x;
      o.y = xv.y + oacc[tt].y;
      o.z = xv.z + oacc[tt].z;
      o.w = xv.w + oacc[tt].w;
      *(float4*)&xT[tok*64 + j0] = o;
    }
  }
}

// ---------------- K/V + gate projection (R8-validated, unchanged) ----------------
__global__ __launch_bounds__(256)
void opt_proj(const float* __restrict__ xT,
              const float* __restrict__ k_w, const float* __restrict__ k_b,
              const float* __restrict__ v_w, const float* __restrict__ v_b,
              const float* __restrict__ g1_w, const float* __restrict__ g1_b,
              const float* __restrict__ g2_w, const float* __restrict__ g2_b,
              float* __restrict__ Kb, float* __restrict__ Vb,
              float* __restrict__ gate)
{
  __shared__ float s_x[64*68];
  const int tid = threadIdx.x;
  const size_t tb = (size_t)blockIdx.x * 64;

  for(int i = tid; i < 64*64; i += 256){
    int t = i >> 6, c = i & 63;
    s_x[t*68 + c] = xT[(tb + t)*64 + c];
  }
  __syncthreads();

  const int r0 = (tid & 15) * 4;
  const int t0 = (tid >> 4) * 4;

  {
    float4 b4 = *(const float4*)&k_b[r0];
    float4 acc[4];
    #pragma unroll
    for(int tt=0;tt<4;tt++) acc[tt] = b4;
    for(int c0=0;c0<64;c0+=4){
      float4 w0 = *(const float4*)&k_w[(r0+0)*64 + c0];
      float4 w1 = *(const float4*)&k_w[(r0+1)*64 + c0];
      float4 w2 = *(const float4*)&k_w[(r0+2)*64 + c0];
      float4 w3 = *(const float4*)&k_w[(r0+3)*64 + c0];
      #pragma unroll
      for(int tt=0;tt<4;tt++){
        float4 x4 = *(const float4*)&s_x[(t0+tt)*68 + c0];
        acc[tt].x = dp4(x4, w0, acc[tt].x);
        acc[tt].y = dp4(x4, w1, acc[tt].y);
        acc[tt].z = dp4(x4, w2, acc[tt].z);
        acc[tt].w = dp4(x4, w3, acc[tt].w);
      }
    }
    #pragma unroll
    for(int tt=0;tt<4;tt++)
      *(float4*)&Kb[(tb + t0 + tt)*64 + r0] = acc[tt];
  }

  {
    float4 b4 = *(const float4*)&v_b[r0];
    float4 acc[4];
    #pragma unroll
    for(int tt=0;tt<4;tt++) acc[tt] = b4;
    for(int c0=0;c0<64;c0+=4){
      float4 w0 = *(const float4*)&v_w[(r0+0)*64 + c0];
      float4 w1 = *(const float4*)&v_w[(r0+1)*64 + c0];
      float4 w2 = *(const float4*)&v_w[(r0+2)*64 + c0];
      float4 w3 = *(const float4*)&v_w[(r0+3)*64 + c0];
      #pragma unroll
      for(int tt=0;tt<4;tt++){
        float4 x4 = *(const float4*)&s_x[(t0+tt)*68 + c0];
        acc[tt].x = dp4(x4, w0, acc[tt].x);
        acc[tt].y = dp4(x4, w1, acc[tt].y);
        acc[tt].z = dp4(x4, w2, acc[tt].z);
        acc[tt].w = dp4(x4, w3, acc[tt].w);
      }
    }
    #pragma unroll
    for(int tt=0;tt<4;tt++)
      *(float4*)&Vb[(tb + t0 + tt)*64 + r0] = acc[tt];
  }

  {
    const int td = tid >> 2;
    const int sr = (tid & 3) * 4;
    float partial = 0.f;
    #pragma unroll
    for(int i=0;i<4;i++){
      int r = sr + i;
      float u = dot64(&s_x[td*68], g1_w + r*64, g1_b[r]);
      u = 0.5f * u * (1.f + erff(u * 0.70710678118654752f));
      partial = fmaf(u, g2_w[r], partial);
    }
    partial += __shfl_xor(partial, 1, 64);
    partial += __shfl_xor(partial, 2, 64);
    if((tid & 3) == 0)
      gate[tb + td] = 1.f / (1.f + __expf(-(partial + g2_b[0])));
  }
}

// ---------------- R9 tile attention (validated, unchanged) ----------------
__global__ __launch_bounds__(256)
void opt_attn3(const float* __restrict__ xT,
               const float* __restrict__ Kb, const float* __restrict__ Vb,
               const float* __restrict__ gate, const int* __restrict__ nbr,
               const float* __restrict__ q_w, const float* __restrict__ q_b,
               const float* __restrict__ o_w, const float* __restrict__ o_b,
               const float* __restrict__ ln2_g, const float* __restrict__ ln2_b,
               float* __restrict__ out)
{
  __shared__ float s_x[64*68];
  __shared__ float s_q[64*68];
  const int tid = threadIdx.x;
  const size_t tb = (size_t)blockIdx.x * 64;

  for(int i = tid; i < 64*64; i += 256){
    int t = i >> 6, c = i & 63;
    s_x[t*68 + c] = xT[(tb + t)*64 + c];
  }
  __syncthreads();

  {
    const int r0 = (tid & 15) * 4, t0 = (tid >> 4) * 4;
    float4 b4 = *(const float4*)&q_b[r0];
    float4 acc[4];
    #pragma unroll
    for(int tt=0;tt<4;tt++) acc[tt] = b4;
    for(int c0=0;c0<64;c0+=4){
      float4 w0 = *(const float4*)&q_w[(r0+0)*64 + c0];
      float4 w1 = *(const float4*)&q_w[(r0+1)*64 + c0];
      float4 w2 = *(const float4*)&q_w[(r0+2)*64 + c0];
      float4 w3 = *(const float4*)&q_w[(r0+3)*64 + c0];
      #pragma unroll
      for(int tt=0;tt<4;tt++){
        float4 x4 = *(const float4*)&s_x[(t0+tt)*68 + c0];
        acc[tt].x = dp4(x4, w0, acc[tt].x);
        acc[tt].y = dp4(x4, w1, acc[tt].y);
        acc[tt].z = dp4(x4, w2, acc[tt].z);
        acc[tt].w = dp4(x4, w3, acc[tt].w);
      }
    }
    #pragma unroll
    for(int tt=0;tt<4;tt++)
      *(float4*)&s_q[(t0+tt)*68 + r0] = acc[tt];
  }
  __syncthreads();

  const int td = tid >> 2, h = tid & 3;
  const size_t idxg = tb + td;
  const int n  = (int)(idxg % NODES);
  const int bt = (int)(idxg / NODES);

  const float* qp = &s_q[td*68 + h*16];
  float4 q0 = *(const float4*)(qp+0);
  float4 q1 = *(const float4*)(qp+4);
  float4 q2 = *(const float4*)(qp+8);
  float4 q3 = *(const float4*)(qp+12);
  int rows[TOPK];
  #pragma unroll
  for(int k=0;k<TOPK;k++) rows[k] = bt*NODES + nbr[n*TOPK + k];
  __syncthreads();

  float sc[TOPK];
  #pragma unroll
  for(int k=0;k<TOPK;k++){
    const float* kr = &Kb[(size_t)rows[k]*64 + h*16];
    float4 k0 = *(const float4*)(kr+0);
    float4 k1 = *(const float4*)(kr+4);
    float4 k2 = *(const float4*)(kr+8);
    float4 k3 = *(const float4*)(kr+12);
    float s = dp4(q0,k0, dp4(q1,k1, dp4(q2,k2, dp4(q3,k3, 0.f))));
    sc[k] = s * 0.25f;
  }
  float mx = sc[0];
  #pragma unroll
  for(int k=1;k<TOPK;k++) mx = fmaxf(mx, sc[k]);
  float ssum = 0.f;
  #pragma unroll
  for(int k=0;k<TOPK;k++){ sc[k] = __expf(sc[k]-mx); ssum += sc[k]; }
  float inv = 1.f/ssum;
  float4 o0 = make_float4(0.f,0.f,0.f,0.f), o1 = o0, o2 = o0, o3 = o0;
  #pragma unroll
  for(int k=0;k<TOPK;k++){
    const float* vr = &Vb[(size_t)rows[k]*64 + h*16];
    float p = sc[k]*inv;
    o0 = f4fma(p, *(const float4*)(vr+0),  o0);
    o1 = f4fma(p, *(const float4*)(vr+4),  o1);
    o2 = f4fma(p, *(const float4*)(vr+8),  o2);
    o3 = f4fma(p, *(const float4*)(vr+12), o3);
  }
  {
    float* op = &s_q[td*68 + h*16];
    *(float4*)(op+0)  = o0;
    *(float4*)(op+4)  = o1;
    *(float4*)(op+8)  = o2;
    *(float4*)(op+12) = o3;
  }
  __syncthreads();

  float4 ores[4];
  const int r0 = (tid & 15) * 4, t0 = (tid >> 4) * 4;
  {
    float4 b4 = *(const float4*)&o_b[r0];
    float4 acc[4];
    #pragma unroll
    for(int tt=0;tt<4;tt++) acc[tt] = b4;
    for(int c0=0;c0<64;c0+=4){
      float4 w0 = *(const float4*)&o_w[(r0+0)*64 + c0];
      float4 w1 = *(const float4*)&o_w[(r0+1)*64 + c0];
      float4 w2 = *(const float4*)&o_w[(r0+2)*64 + c0];
      float4 w3 = *(const float4*)&o_w[(r0+3)*64 + c0];
      #pragma unroll
      for(int tt=0;tt<4;tt++){
        float4 g4 = *(const float4*)&s_q[(t0+tt)*68 + c0];
        acc[tt].x = dp4(g4, w0, acc[tt].x);
        acc[tt].y = dp4(g4, w1, acc[tt].y);
        acc[tt].z = dp4(g4, w2, acc[tt].z);
        acc[tt].w = dp4(g4, w3, acc[tt].w);
      }
    }
    #pragma unroll
    for(int tt=0;tt<4;tt++){
      float g = gate[tb + t0 + tt];
      float4 xv = *(const float4*)&s_x[(t0+tt)*68 + r0];
      ores[tt].x = xv.x + g*(acc[tt].x - xv.x);
      ores[tt].y = xv.y + g*(acc[tt].y - xv.y);
      ores[tt].z = xv.z + g*(acc[tt].z - xv.z);
      ores[tt].w = xv.w + g*(acc[tt].w - xv.w);
    }
  }
  __syncthreads();
  #pragma unroll
  for(int tt=0;tt<4;tt++)
    *(float4*)&s_q[(t0+tt)*68 + r0] = ores[tt];
  __syncthreads();

  {
    const float* orow = &s_q[td*68 + h*16];
    float4 a0 = *(const float4*)(orow+0);
    float4 a1 = *(const float4*)(orow+4);
    float4 a2 = *(const float4*)(orow+8);
    float4 a3 = *(const float4*)(orow+12);
    float sum = (a0.x+a0.y+a0.z+a0.w) + (a1.x+a1.y+a1.z+a1.w)
              + (a2.x+a2.y+a2.z+a2.w) + (a3.x+a3.y+a3.z+a3.w);
    sum += __shfl_xor(sum, 1, 64);
    sum += __shfl_xor(sum, 2, 64);
    float mean = sum * (1.f/64.f);
    a0.x-=mean; a0.y-=mean; a0.z-=mean; a0.w-=mean;
    a1.x-=mean; a1.y-=mean; a1.z-=mean; a1.w-=mean;
    a2.x-=mean; a2.y-=mean; a2.z-=mean; a2.w-=mean;
    a3.x-=mean; a3.y-=mean; a3.z-=mean; a3.w-=mean;
    float sq = (a0.x*a0.x+a0.y*a0.y+a0.z*a0.z+a0.w*a0.w)
             + (a1.x*a1.x+a1.y*a1.y+a1.z*a1.z+a1.w*a1.w)
             + (a2.x*a2.x+a2.y*a2.y+a2.z*a2.z+a2.w*a2.w)
             + (a3.x*a3.x+a3.y*a3.y+a3.z*a3.z+a3.w*a3.w);
    sq += __shfl_xor(sq, 1, 64);
    sq += __shfl_xor(sq, 2, 64);
    float rstd = rsqrtf(sq*(1.f/64.f) + EPS);
    float4 g0 = *(const float4*)&ln2_g[h*16+0];
    float4 g1 = *(const float4*)&ln2_g[h*16+4];
    float4 g2 = *(const float4*)&ln2_g[h*16+8];
    float4 g3 = *(const float4*)&ln2_g[h*16+12];
    float4 bb0 = *(const float4*)&ln2_b[h*16+0];
    float4 bb1 = *(const float4*)&ln2_b[h*16+4];
    float4 bb2 = *(const float4*)&ln2_b[h*16+8];
    float4 bb3 = *(const float4*)&ln2_b[h*16+12];
    float* po = &out[idxg*64 + h*16];
    float4 r;
    r.x=a0.x*rstd*g0.x+bb0.x; r.y=a0.y*rstd*g0.y+bb0.y; r.z=a0.z*rstd*g0.z+bb0.z; r.w=a0.w*rstd*g0.w+bb0.w;
    *(float4*)(po+0) = r;
    r.x=a1.x*rstd*g1.x+bb1.x; r.y=a1.y*rstd*g1.y+bb1.y; r.z=a1.z*rstd*g1.z+bb1.z; r.w=a1.w*rstd*g1.w+bb1.w;
    *(float4*)(po+4) = r;
    r.x=a2.x*rstd*g2.x+bb2.x; r.y=a2.y*rstd*g2.y+bb2.y; r.z=a2.z*rstd*g2.z+bb2.z; r.w=a2.w*rstd*g2.w+bb2.w;
    *(float4*)(po+8) = r;
    r.x=a3.x*rstd*g3.x+bb3.x; r.y=a3.y*rstd*g3.y+bb3.y; r.z=a3.z*rstd*g3.z+bb3.z; r.w=a3.w*rstd*g3.w+bb3.w;
    *(float4*)(po+12) = r;
  }
}

// ---------------- Fallback fused attn (used only if ws too small) ----------------
__global__ __launch_bounds__(64)
void opt_attn(const float* __restrict__ xT, const int* __restrict__ nbr,
              const float* __restrict__ q_w, const float* __restrict__ q_b,
              const float* __restrict__ k_w, const float* __restrict__ k_b,
              const float* __restrict__ v_w, const float* __restrict__ v_b,
              const float* __restrict__ o_w, const float* __restrict__ o_b,
              const float* __restrict__ g1_w, const float* __restrict__ g1_b,
              const float* __restrict__ g2_w, const float* __restrict__ g2_b,
              const float* __restrict__ ln2_g, const float* __restrict__ ln2_b,
              float* __restrict__ out)
{
  const int idx = blockIdx.x;
  const int n   = idx % NODES;
  const int bt  = idx / NODES;
  const int j   = threadIdx.x;

  __shared__ float s_x[64];
  __shared__ float s_nb[TOPK][64];
  __shared__ float s_og[64];
  __shared__ float s_gate;

  float xv = xT[(size_t)idx*64 + j];
  s_x[j] = xv;
  const int base = bt * NODES;
  #pragma unroll
  for(int k=0;k<TOPK;k++){
    int nb2 = nbr[n*TOPK + k];
    s_nb[k][j] = xT[(size_t)(base + nb2)*64 + j];
  }
  __syncthreads();

  float Qj = dot64(s_x, q_w + j*64, q_b[j]);

  float sc[TOPK], vv[TOPK];
  #pragma unroll
  for(int k=0;k<TOPK;k++){
    float Kk = dot64(s_nb[k], k_w + j*64, k_b[j]);
    vv[k]    = dot64(s_nb[k], v_w + j*64, v_b[j]);
    sc[k]    = groupSum16(Qj * Kk) * 0.25f;
  }
  float m = sc[0];
  #pragma unroll
  for(int k=1;k<TOPK;k++) m = fmaxf(m, sc[k]);
  float ssum = 0.f;
  #pragma unroll
  for(int k=0;k<TOPK;k++){ sc[k] = __expf(sc[k]-m); ssum += sc[k]; }
  float inv = 1.f/ssum;
  float og = 0.f;
  #pragma unroll
  for(int k=0;k<TOPK;k++) og = fmaf(sc[k]*inv, vv[k], og);
  s_og[j] = og;
  __syncthreads();

  float xg = dot64(s_og, o_w + j*64, o_b[j]);

  if(j < 16){
    float u = dot64(s_x, g1_w + j*64, g1_b[j]);
    u = 0.5f * u * (1.f + erff(u * 0.70710678118654752f));
    float contrib = groupSum16(u * g2_w[j]);
    if(j == 0) s_gate = 1.f / (1.f + __expf(-(contrib + g2_b[0])));
  }
  __syncthreads();

  float gg = s_gate;
  float o  = xv + gg * (xg - xv);

  float mm  = waveSum64(o) * (1.f/64.f);
  float c   = o - mm;
  float var = waveSum64(c*c) * (1.f/64.f);
  out[(size_t)idx*64 + j] = c * rsqrtf(var + EPS) * ln2_g[j] + ln2_b[j];
}

extern "C" void kernel_launch(void* const* d_in, const int* in_sizes, int n_in,
                              void* d_out, int out_size, void* d_ws, size_t ws_size,
                              hipStream_t stream)
{
  const float* x      = (const float*)d_in[0];
  const int*   nbr    = (const int*  )d_in[1];
  const float* ln1_g  = (const float*)d_in[2];
  const float* ln1_b  = (const float*)d_in[3];
  const float* in_w   = (const float*)d_in[4];
  const float* conv_w = (const float*)d_in[5];
  const float* conv_b = (const float*)d_in[6];
  const float* xp_w   = (const float*)d_in[7];
  const float* dt_w   = (const float*)d_in[8];
  const float* dt_b   = (const float*)d_in[9];
  const float* A_log  = (const float*)d_in[10];
  const float* Dss    = (const float*)d_in[11];
  const float* out_w  = (const float*)d_in[12];
  const float* q_w    = (const float*)d_in[13];
  const float* q_b    = (const float*)d_in[14];
  const float* k_w    = (const float*)d_in[15];
  const float* k_b    = (const float*)d_in[16];
  const float* v_w    = (const float*)d_in[17];
  const float* v_b    = (const float*)d_in[18];
  const float* o_w    = (const float*)d_in[19];
  const float* o_b    = (const float*)d_in[20];
  const float* g1_w   = (const float*)d_in[21];
  const float* g1_b   = (const float*)d_in[22];
  const float* g2_w   = (const float*)d_in[23];
  const float* g2_b   = (const float*)d_in[24];
  const float* ln2_g  = (const float*)d_in[25];
  const float* ln2_b  = (const float*)d_in[26];

  float* xT   = (float*)d_ws;                 // 42.6 MB
  float* Kb   = xT + NTOK*64;                 // +42.6 MB
  float* Vb   = Kb + NTOK*64;                 // +42.6 MB
  float* gg   = Vb + NTOK*64;                 // +0.67 MB
  float* outp = (float*)d_out;

  const size_t need = (NTOK*64*3 + NTOK) * sizeof(float);   // ~128.5 MB (proven R2-R7)

  (void)hipFuncSetAttribute(reinterpret_cast<const void*>(opt_mamba),
                            hipFuncAttributeMaxDynamicSharedMemorySize, SMEM_BYTES);

  opt_mamba<<<dim3(B_SZ*NODES), dim3(512), SMEM_BYTES, stream>>>(
      x, ln1_g, ln1_b, in_w, conv_w, conv_b, xp_w, dt_w, dt_b, A_log, Dss, out_w, xT);

  if(ws_size >= need){
    opt_proj<<<dim3((unsigned)(NTOK/64)), dim3(256), 0, stream>>>(
        xT, k_w, k_b, v_w, v_b, g1_w, g1_b, g2_w, g2_b, Kb, Vb, gg);
    opt_attn3<<<dim3((unsigned)(NTOK/64)), dim3(256), 0, stream>>>(
        xT, Kb, Vb, gg, nbr, q_w, q_b, o_w, o_b, ln2_g, ln2_b, outp);
  } else {
    opt_attn<<<dim3((unsigned)NTOK), dim3(64), 0, stream>>>(
        xT, nbr, q_w, q_b, k_w, k_b, v_w, v_b, o_w, o_b,
        g1_w, g1_b, g2_w, g2_b, ln2_g, ln2_b, outp);
  }
}